// Round 13
// baseline (480.135 us; speedup 1.0000x reference)
//
#include <hip/hip_runtime.h>

// Problem constants
#define P_TOTAL   32768      // 8*64*64 patches
#define C_DIM     64         // patch dim / channels
#define N_ATOMS   512
#define K_SP      5
#define HW_DIM    4096       // 64*64
#define OUT_ZDL   2097152    // 8*64*64*64
#define OUT_LOSS  2097152
#define OUT_COEFF 2097153
#define COEFF_N   16777216   // 512*32768
#define NBLOCKS_OMP (P_TOTAL / 8)   // 4096 blocks, 4 waves x 2 patches

// ---------------- zero the loss + coeffs region ----------------
__global__ void zero_tail(float* __restrict__ out) {
    float4* base = reinterpret_cast<float4*>(out + OUT_LOSS);
    const unsigned n4 = 4194304;  // 16777216/4
    unsigned stride = gridDim.x * blockDim.x;
    for (unsigned i = blockIdx.x * blockDim.x + threadIdx.x; i < n4; i += stride)
        base[i] = float4{0.f, 0.f, 0.f, 0.f};
    if (blockIdx.x == 0 && threadIdx.x == 0)
        out[OUT_LOSS + 16777216] = 0.f;
}

// ---------------- prep: G = D^T D + eps I (f64), Dt = D^T (f32) ----------------
__global__ void prep_kernel(const float* __restrict__ D,
                            double* __restrict__ G,
                            float* __restrict__ Dt) {
    int tid = blockIdx.x * blockDim.x + threadIdx.x;  // 1024*256 = 262144
    int i = tid >> 9;
    int j = tid & 511;
    double s = 0.0;
    #pragma unroll
    for (int m = 0; m < 64; ++m)
        s += (double)D[m * 512 + i] * (double)D[m * 512 + j];
    if (i == j) s += 1e-5;
    G[(size_t)i * 512 + j] = s;
    if (tid < N_ATOMS * C_DIM) {
        int n = tid >> 6, m = tid & 63;
        Dt[n * 64 + m] = D[m * 512 + n];
    }
}

// ---------------- fused OMP, 2 patches per wave (shared D stream) ----------
// Lane owns atoms n = lane*8 + j. h_bar summation: c ascending, per-atom —
// bit-identical per patch to the verified round-7/10 kernels. D is loaded
// and converted to f64 ONCE per wave per c, used by both patches.
__launch_bounds__(256)
__global__ void omp4_kernel(const float* __restrict__ ze,
                            const float* __restrict__ D,
                            const double* __restrict__ G,
                            const float* __restrict__ Dt,
                            float* __restrict__ out,
                            double* __restrict__ lpart) {
    __shared__ float sp[4][2][64];
    __shared__ double lsum[4];
    const int wave = threadIdx.x >> 6;
    const int lane = threadIdx.x & 63;
    const int p0   = blockIdx.x * 8 + wave * 2;   // patches p0, p0+1
    const int b    = p0 >> 12;                    // p0 even -> both patches same b
    const int hw0  = p0 & 4095;                   // hw0 even, hw0+1 <= 4095

    // two adjacent hw elements -> one float2 load per lane
    float pe[2];
    {
        const float2 v = *reinterpret_cast<const float2*>(
            ze + (size_t)(b * 64 + lane) * 4096 + hw0);
        pe[0] = v.x; pe[1] = v.y;
        sp[wave][0][lane] = v.x;
        sp[wave][1][lane] = v.y;
    }
    __syncthreads();

    // ---- h_bar for both patches, shared D load+cvt ----
    double hb[2][8];
    #pragma unroll
    for (int q = 0; q < 2; ++q)
        #pragma unroll
        for (int j = 0; j < 8; ++j) hb[q][j] = 0.0;

    for (int c = 0; c < 64; ++c) {
        const float4 d0 = *reinterpret_cast<const float4*>(D + c * 512 + lane * 8);
        const float4 d1 = *reinterpret_cast<const float4*>(D + c * 512 + lane * 8 + 4);
        double dd[8];
        dd[0] = (double)d0.x; dd[1] = (double)d0.y; dd[2] = (double)d0.z; dd[3] = (double)d0.w;
        dd[4] = (double)d1.x; dd[5] = (double)d1.y; dd[6] = (double)d1.z; dd[7] = (double)d1.w;
        const double pc0 = (double)sp[wave][0][c];
        const double pc1 = (double)sp[wave][1][c];
        #pragma unroll
        for (int j = 0; j < 8; ++j) {
            hb[0][j] += pc0 * dd[j];
            hb[1][j] += pc1 * dd[j];
        }
    }

    double h[2][8];
    #pragma unroll
    for (int q = 0; q < 2; ++q)
        #pragma unroll
        for (int j = 0; j < 8; ++j) h[q][j] = hb[q][j];

    unsigned mask[2] = {0, 0};
    int    a[2][5];
    double rhs[2][5];
    double x[2][5];

    #pragma unroll
    for (int k = 0; k < K_SP; ++k) {
        // ---- local argmax for both patches ----
        double bv[2]; int bn[2];
        #pragma unroll
        for (int q = 0; q < 2; ++q) {
            bv[q] = -1.0; bn[q] = 0x7fffffff;
            #pragma unroll
            for (int j = 0; j < 8; ++j) {
                double av = fabs(h[q][j]);
                bool ok = !((mask[q] >> j) & 1u);
                int n = lane * 8 + j;
                if (ok && (av > bv[q] || (av == bv[q] && n < bn[q]))) { bv[q] = av; bn[q] = n; }
            }
        }
        // ---- wave argmax reduce, both patches interleaved (independent) ----
        #pragma unroll
        for (int off = 32; off > 0; off >>= 1) {
            #pragma unroll
            for (int q = 0; q < 2; ++q) {
                double ov = __shfl_xor(bv[q], off);
                int    on = __shfl_xor(bn[q], off);
                if (ov > bv[q] || (ov == bv[q] && on < bn[q])) { bv[q] = ov; bn[q] = on; }
            }
        }
        #pragma unroll
        for (int q = 0; q < 2; ++q) {
            a[q][k] = bn[q];
            const int src = bn[q] >> 3, jj = bn[q] & 7;
            double v = 0.0;
            #pragma unroll
            for (int j = 0; j < 8; ++j) if (j == jj) v = hb[q][j];
            rhs[q][k] = __shfl(v, src);
            if (lane == src) mask[q] |= (1u << jj);
        }

        // ---- solve (k+1)x(k+1) per patch (scoped so T/y regs are reused) ----
        #pragma unroll
        for (int q = 0; q < 2; ++q) {
            double T[5][5], y[5];
            #pragma unroll
            for (int i = 0; i <= k; ++i) {
                #pragma unroll
                for (int j2 = 0; j2 <= k; ++j2)
                    T[i][j2] = G[(size_t)a[q][i] * 512 + a[q][j2]];
                y[i] = rhs[q][i];
            }
            #pragma unroll
            for (int col = 0; col <= k; ++col) {
                double inv = 1.0 / T[col][col];
                #pragma unroll
                for (int r = col + 1; r <= k; ++r) {
                    double f = T[r][col] * inv;
                    #pragma unroll
                    for (int cc = col; cc <= k; ++cc)
                        T[r][cc] -= f * T[col][cc];
                    y[r] -= f * y[col];
                }
            }
            #pragma unroll
            for (int r = k; r >= 0; --r) {
                double s = y[r];
                #pragma unroll
                for (int cc = r + 1; cc <= k; ++cc) s -= T[r][cc] * x[q][cc];
                x[q][r] = s / T[r][r];
            }
        }

        // ---- residual per patch: h = hb - sum_i x[i]*G[a[i]] (i ascending) ----
        if (k < K_SP - 1) {
            #pragma unroll
            for (int q = 0; q < 2; ++q) {
                #pragma unroll
                for (int j = 0; j < 8; ++j) h[q][j] = hb[q][j];
                #pragma unroll
                for (int i = 0; i <= k; ++i) {
                    const double2* gr = reinterpret_cast<const double2*>(
                        G + (size_t)a[q][i] * 512 + lane * 8);
                    double2 g0 = gr[0], g1 = gr[1], g2 = gr[2], g3 = gr[3];
                    const double xi = x[q][i];
                    h[q][0] -= xi * g0.x; h[q][1] -= xi * g0.y;
                    h[q][2] -= xi * g1.x; h[q][3] -= xi * g1.y;
                    h[q][4] -= xi * g2.x; h[q][5] -= xi * g2.y;
                    h[q][6] -= xi * g3.x; h[q][7] -= xi * g3.y;
                }
            }
        }
    }

    // ---- scatter coeffs.T for both patches ----
    if (lane == 0) {
        #pragma unroll
        for (int q = 0; q < 2; ++q)
            #pragma unroll
            for (int i = 0; i < K_SP; ++i)
                out[(size_t)OUT_COEFF + (size_t)a[q][i] * 32768 + (p0 + q)] = (float)x[q][i];
    }

    // ---- recon, z_dl_st (adjacent hw -> float2 store), loss ----
    float zd[2];
    #pragma unroll
    for (int q = 0; q < 2; ++q) {
        double rc = 0.0;
        #pragma unroll
        for (int i = 0; i < K_SP; ++i)
            rc += x[q][i] * (double)Dt[(size_t)a[q][i] * 64 + lane];
        zd[q] = (float)rc;
    }
    {
        float2 st;
        st.x = pe[0] + (zd[0] - pe[0]);
        st.y = pe[1] + (zd[1] - pe[1]);
        *reinterpret_cast<float2*>(out + (size_t)(b * 64 + lane) * 4096 + hw0) = st;
    }

    const float df0 = zd[0] - pe[0];
    const float df1 = zd[1] - pe[1];
    double sq = (double)df0 * (double)df0 + (double)df1 * (double)df1;
    #pragma unroll
    for (int off = 32; off > 0; off >>= 1)
        sq += __shfl_xor(sq, off);
    if (lane == 0) lsum[wave] = sq;
    __syncthreads();
    if (threadIdx.x == 0)
        lpart[blockIdx.x] = (lsum[0] + lsum[1]) + (lsum[2] + lsum[3]);
}

// ---------------- final loss reduction: 4096 f64 partials -> out[OUT_LOSS] ----
__global__ void loss_reduce(const double* __restrict__ lpart,
                            float* __restrict__ out) {
    __shared__ double ls[4];
    const int tid = threadIdx.x, wave = tid >> 6, lane = tid & 63;
    double s = 0.0;
    for (int i = tid; i < NBLOCKS_OMP; i += 256) s += lpart[i];
    #pragma unroll
    for (int off = 32; off > 0; off >>= 1)
        s += __shfl_xor(s, off);
    if (lane == 0) ls[wave] = s;
    __syncthreads();
    if (tid == 0)
        out[OUT_LOSS] = (float)(((ls[0] + ls[1]) + (ls[2] + ls[3])) * (1.25 / 2097152.0));
}

extern "C" void kernel_launch(void* const* d_in, const int* in_sizes, int n_in,
                              void* d_out, int out_size, void* d_ws, size_t ws_size,
                              hipStream_t stream) {
    const float* ze = (const float*)d_in[0];   // (8,64,64,64) f32
    const float* D  = (const float*)d_in[1];   // (64,512) f32, unit-norm cols
    float* out = (float*)d_out;

    const size_t G_BYTES  = (size_t)512 * 512 * 8;       // 2097152
    const size_t DT_BYTES = (size_t)512 * 64 * 4;        // 131072

    double* G  = (double*)d_ws;
    float*  Dt = (float*)((char*)d_ws + G_BYTES);
    double* LP = (double*)((char*)d_ws + G_BYTES + DT_BYTES);

    zero_tail<<<2048, 256, 0, stream>>>(out);
    prep_kernel<<<1024, 256, 0, stream>>>(D, G, Dt);
    omp4_kernel<<<NBLOCKS_OMP, 256, 0, stream>>>(ze, D, G, Dt, out, LP);
    loss_reduce<<<1, 256, 0, stream>>>(LP, out);
}

// Round 14
// 326.064 us; speedup vs baseline: 1.4725x; 1.4725x over previous
//
#include <hip/hip_runtime.h>

// Problem constants
#define P_TOTAL   32768      // 8*64*64 patches
#define C_DIM     64         // patch dim / channels
#define N_ATOMS   512
#define K_SP      5
#define HW_DIM    4096       // 64*64
#define OUT_ZDL   2097152    // 8*64*64*64
#define OUT_LOSS  2097152
#define OUT_COEFF 2097153
#define COEFF_N   16777216   // 512*32768
#define NBLOCKS_OMP (P_TOTAL / 4)   // 8192

// ---------------- zero the loss + coeffs region ----------------
__global__ void zero_tail(float* __restrict__ out) {
    float4* base = reinterpret_cast<float4*>(out + OUT_LOSS);
    const unsigned n4 = 4194304;  // 16777216/4
    unsigned stride = gridDim.x * blockDim.x;
    for (unsigned i = blockIdx.x * blockDim.x + threadIdx.x; i < n4; i += stride)
        base[i] = float4{0.f, 0.f, 0.f, 0.f};
    if (blockIdx.x == 0 && threadIdx.x == 0)
        out[OUT_LOSS + 16777216] = 0.f;
}

// ---------------- prep: G = D^T D + eps I (f64), Dt = D^T (f32) ----------------
__global__ void prep_kernel(const float* __restrict__ D,
                            double* __restrict__ G,
                            float* __restrict__ Dt) {
    int tid = blockIdx.x * blockDim.x + threadIdx.x;  // 1024*256 = 262144
    int i = tid >> 9;
    int j = tid & 511;
    double s = 0.0;
    #pragma unroll
    for (int m = 0; m < 64; ++m)
        s += (double)D[m * 512 + i] * (double)D[m * 512 + j];
    if (i == j) s += 1e-5;
    G[(size_t)i * 512 + j] = s;
    if (tid < N_ATOMS * C_DIM) {
        int n = tid >> 6, m = tid & 63;
        Dt[n * 64 + m] = D[m * 512 + n];
    }
}

// ---------------- h_bar GEMM, LEAN: 4 patches/wave (64 acc VGPRs) ----------
// H[p][n] = sum_c patch[p][c] * D[c][n], f64, c ascending — bit-identical
// per patch to all verified kernels. Block = 4 waves x 4 patches = 16.
__launch_bounds__(256)
__global__ void hbar_kernel(const float* __restrict__ ze,
                            const float* __restrict__ D,
                            double* __restrict__ H) {
    __shared__ float sp[16][64];
    const int tid = threadIdx.x;
    const int p0  = blockIdx.x * 16;

    // stage 16 patches x 64 channels (coalesced over hw for fixed c)
    {
        const int i = tid & 15, c0 = tid >> 4;  // c0 = 0..15
        const int p = p0 + i, b = p >> 12, hw = p & 4095;
        #pragma unroll
        for (int r = 0; r < 4; ++r) {
            int c = c0 * 4 + r;
            sp[i][c] = ze[(size_t)(b * 64 + c) * 4096 + hw];
        }
    }
    __syncthreads();

    const int wave = tid >> 6, lane = tid & 63;
    const int pw = wave * 4;

    double acc[4][8];
    #pragma unroll
    for (int pi = 0; pi < 4; ++pi)
        #pragma unroll
        for (int j = 0; j < 8; ++j) acc[pi][j] = 0.0;

    for (int c = 0; c < 64; ++c) {
        const float4 d0 = *reinterpret_cast<const float4*>(D + c * 512 + lane * 8);
        const float4 d1 = *reinterpret_cast<const float4*>(D + c * 512 + lane * 8 + 4);
        double dd[8];
        dd[0] = (double)d0.x; dd[1] = (double)d0.y; dd[2] = (double)d0.z; dd[3] = (double)d0.w;
        dd[4] = (double)d1.x; dd[5] = (double)d1.y; dd[6] = (double)d1.z; dd[7] = (double)d1.w;
        #pragma unroll
        for (int pi = 0; pi < 4; ++pi) {
            const double pc = (double)sp[pw + pi][c];
            #pragma unroll
            for (int j = 0; j < 8; ++j)
                acc[pi][j] += pc * dd[j];
        }
    }

    #pragma unroll
    for (int pi = 0; pi < 4; ++pi) {
        double* Hp = H + (size_t)(p0 + pw + pi) * 512 + lane * 8;
        #pragma unroll
        for (int t = 0; t < 4; ++t)
            reinterpret_cast<double2*>(Hp)[t] = make_double2(acc[pi][2 * t], acc[pi][2 * t + 1]);
    }
}

// ---------------- OMP iterations: one wave per patch (round-7 verified) ----
__launch_bounds__(256)
__global__ void omp2_kernel(const float* __restrict__ ze,
                            const double* __restrict__ H,
                            const double* __restrict__ G,
                            const float* __restrict__ Dt,
                            float* __restrict__ out,
                            double* __restrict__ lpart) {
    __shared__ double lsum[4];
    const int wave = threadIdx.x >> 6;
    const int lane = threadIdx.x & 63;
    const int p    = blockIdx.x * 4 + wave;
    const int b    = p >> 12;
    const int hw   = p & 4095;

    const float pe = ze[(size_t)(b * 64 + lane) * 4096 + hw];

    double hb[8], h[8];
    {
        const double2* Hp = reinterpret_cast<const double2*>(H + (size_t)p * 512 + lane * 8);
        double2 t0 = Hp[0], t1 = Hp[1], t2 = Hp[2], t3 = Hp[3];
        hb[0] = t0.x; hb[1] = t0.y; hb[2] = t1.x; hb[3] = t1.y;
        hb[4] = t2.x; hb[5] = t2.y; hb[6] = t3.x; hb[7] = t3.y;
    }
    #pragma unroll
    for (int j = 0; j < 8; ++j) h[j] = hb[j];

    unsigned mask = 0;
    int    a[5];
    double rhs[5];
    double x[5];

    #pragma unroll
    for (int k = 0; k < K_SP; ++k) {
        // ---- local argmax of |h| (skip masked), lowest-n tie-break ----
        double bv = -1.0; int bn = 0x7fffffff;
        #pragma unroll
        for (int j = 0; j < 8; ++j) {
            double av = fabs(h[j]);
            bool ok = !((mask >> j) & 1u);
            int n = lane * 8 + j;
            if (ok && (av > bv || (av == bv && n < bn))) { bv = av; bn = n; }
        }
        // ---- wave argmax reduce ----
        #pragma unroll
        for (int off = 32; off > 0; off >>= 1) {
            double ov = __shfl_xor(bv, off);
            int    on = __shfl_xor(bn, off);
            if (ov > bv || (ov == bv && on < bn)) { bv = ov; bn = on; }
        }
        a[k] = bn;
        {
            const int src = bn >> 3, jj = bn & 7;
            double v = 0.0;
            #pragma unroll
            for (int j = 0; j < 8; ++j) if (j == jj) v = hb[j];
            rhs[k] = __shfl(v, src);
            if (lane == src) mask |= (1u << jj);
        }

        // ---- solve (k+1)x(k+1) Gram system, replicated on all lanes ----
        double T[5][5], y[5];
        #pragma unroll
        for (int i = 0; i <= k; ++i) {
            #pragma unroll
            for (int j2 = 0; j2 <= k; ++j2)
                T[i][j2] = G[(size_t)a[i] * 512 + a[j2]];
            y[i] = rhs[i];
        }
        #pragma unroll
        for (int col = 0; col <= k; ++col) {
            double inv = 1.0 / T[col][col];
            #pragma unroll
            for (int r = col + 1; r <= k; ++r) {
                double f = T[r][col] * inv;
                #pragma unroll
                for (int cc = col; cc <= k; ++cc)
                    T[r][cc] -= f * T[col][cc];
                y[r] -= f * y[col];
            }
        }
        #pragma unroll
        for (int r = k; r >= 0; --r) {
            double s = y[r];
            #pragma unroll
            for (int cc = r + 1; cc <= k; ++cc) s -= T[r][cc] * x[cc];
            x[r] = s / T[r][r];
        }

        // ---- residual: h = hb - sum_i x[i]*G[a[i]] (same order -> bit-identical) ----
        if (k < K_SP - 1) {
            #pragma unroll
            for (int j = 0; j < 8; ++j) h[j] = hb[j];
            #pragma unroll
            for (int i = 0; i <= k; ++i) {
                const double2* gr = reinterpret_cast<const double2*>(G + (size_t)a[i] * 512 + lane * 8);
                double2 g0 = gr[0], g1 = gr[1], g2 = gr[2], g3 = gr[3];
                h[0] -= x[i] * g0.x; h[1] -= x[i] * g0.y;
                h[2] -= x[i] * g1.x; h[3] -= x[i] * g1.y;
                h[4] -= x[i] * g2.x; h[5] -= x[i] * g2.y;
                h[6] -= x[i] * g3.x; h[7] -= x[i] * g3.y;
            }
        }
    }

    // ---- scatter coeffs.T ----
    if (lane == 0) {
        #pragma unroll
        for (int i = 0; i < K_SP; ++i)
            out[(size_t)OUT_COEFF + (size_t)a[i] * 32768 + p] = (float)x[i];
    }

    // ---- recon, z_dl_st ----
    double rc = 0.0;
    #pragma unroll
    for (int i = 0; i < K_SP; ++i)
        rc += x[i] * (double)Dt[(size_t)a[i] * 64 + lane];
    const float zd = (float)rc;
    out[(size_t)(b * 64 + lane) * 4096 + hw] = pe + (zd - pe);

    // ---- loss: wave reduce -> block partial (no global atomic) ----
    const float df = zd - pe;
    double sq = (double)df * (double)df;
    #pragma unroll
    for (int off = 32; off > 0; off >>= 1)
        sq += __shfl_xor(sq, off);
    if (lane == 0) lsum[wave] = sq;
    __syncthreads();
    if (threadIdx.x == 0)
        lpart[blockIdx.x] = (lsum[0] + lsum[1]) + (lsum[2] + lsum[3]);
}

// ---------------- final loss reduction: 8192 f64 partials -> out[OUT_LOSS] ----
__global__ void loss_reduce(const double* __restrict__ lpart,
                            float* __restrict__ out) {
    __shared__ double ls[4];
    const int tid = threadIdx.x, wave = tid >> 6, lane = tid & 63;
    double s = 0.0;
    for (int i = tid; i < NBLOCKS_OMP; i += 256) s += lpart[i];
    #pragma unroll
    for (int off = 32; off > 0; off >>= 1)
        s += __shfl_xor(s, off);
    if (lane == 0) ls[wave] = s;
    __syncthreads();
    if (tid == 0)
        out[OUT_LOSS] = (float)(((ls[0] + ls[1]) + (ls[2] + ls[3])) * (1.25 / 2097152.0));
}

extern "C" void kernel_launch(void* const* d_in, const int* in_sizes, int n_in,
                              void* d_out, int out_size, void* d_ws, size_t ws_size,
                              hipStream_t stream) {
    const float* ze = (const float*)d_in[0];   // (8,64,64,64) f32
    const float* D  = (const float*)d_in[1];   // (64,512) f32, unit-norm cols
    float* out = (float*)d_out;

    const size_t H_BYTES  = (size_t)P_TOTAL * 512 * 8;   // 134217728
    const size_t G_BYTES  = (size_t)512 * 512 * 8;       // 2097152
    const size_t DT_BYTES = (size_t)512 * 64 * 4;        // 131072

    double* H  = (double*)d_ws;
    double* G  = (double*)((char*)d_ws + H_BYTES);
    float*  Dt = (float*)((char*)d_ws + H_BYTES + G_BYTES);
    double* LP = (double*)((char*)d_ws + H_BYTES + G_BYTES + DT_BYTES);

    zero_tail<<<2048, 256, 0, stream>>>(out);
    prep_kernel<<<1024, 256, 0, stream>>>(D, G, Dt);
    hbar_kernel<<<P_TOTAL / 16, 256, 0, stream>>>(ze, D, H);
    omp2_kernel<<<NBLOCKS_OMP, 256, 0, stream>>>(ze, H, G, Dt, out, LP);
    loss_reduce<<<1, 256, 0, stream>>>(LP, out);
}

// Round 15
// 274.355 us; speedup vs baseline: 1.7501x; 1.1885x over previous
//
#include <hip/hip_runtime.h>

// Problem constants
#define P_TOTAL   32768      // 8*64*64 patches
#define C_DIM     64         // patch dim / channels
#define N_ATOMS   512
#define K_SP      5
#define HW_DIM    4096       // 64*64
#define OUT_ZDL   2097152    // 8*64*64*64
#define OUT_LOSS  2097152
#define OUT_COEFF 2097153
#define COEFF_N   16777216   // 512*32768
#define NBLOCKS_OMP (P_TOTAL / 4)   // 8192

// ---------------- zero the loss + coeffs region ----------------
__global__ void zero_tail(float* __restrict__ out) {
    float4* base = reinterpret_cast<float4*>(out + OUT_LOSS);
    const unsigned n4 = 4194304;  // 16777216/4
    unsigned stride = gridDim.x * blockDim.x;
    for (unsigned i = blockIdx.x * blockDim.x + threadIdx.x; i < n4; i += stride)
        base[i] = float4{0.f, 0.f, 0.f, 0.f};
    if (blockIdx.x == 0 && threadIdx.x == 0)
        out[OUT_LOSS + 16777216] = 0.f;
}

// ---------------- prep: G (f64) + Gf (f32) + Dt (f32) ----------------
__global__ void prep_kernel(const float* __restrict__ D,
                            double* __restrict__ G,
                            float* __restrict__ Gf,
                            float* __restrict__ Dt) {
    int tid = blockIdx.x * blockDim.x + threadIdx.x;  // 1024*256 = 262144
    int i = tid >> 9;
    int j = tid & 511;
    double s = 0.0;
    #pragma unroll
    for (int m = 0; m < 64; ++m)
        s += (double)D[m * 512 + i] * (double)D[m * 512 + j];
    if (i == j) s += 1e-5;
    G[(size_t)i * 512 + j] = s;
    Gf[(size_t)i * 512 + j] = (float)s;
    if (tid < N_ATOMS * C_DIM) {
        int n = tid >> 6, m = tid & 63;
        Dt[n * 64 + m] = D[m * 512 + n];
    }
}

// ---------------- h_bar GEMM, f32: 4 patches/wave (32 acc VGPRs) ----------
// H[p][n] = sum_c patch[p][c] * D[c][n], f32, c ascending.
__launch_bounds__(256)
__global__ void hbar_kernel(const float* __restrict__ ze,
                            const float* __restrict__ D,
                            float* __restrict__ H) {
    __shared__ float sp[16][64];
    const int tid = threadIdx.x;
    const int p0  = blockIdx.x * 16;

    {
        const int i = tid & 15, c0 = tid >> 4;  // c0 = 0..15
        const int p = p0 + i, b = p >> 12, hw = p & 4095;
        #pragma unroll
        for (int r = 0; r < 4; ++r) {
            int c = c0 * 4 + r;
            sp[i][c] = ze[(size_t)(b * 64 + c) * 4096 + hw];
        }
    }
    __syncthreads();

    const int wave = tid >> 6, lane = tid & 63;
    const int pw = wave * 4;

    float acc[4][8];
    #pragma unroll
    for (int pi = 0; pi < 4; ++pi)
        #pragma unroll
        for (int j = 0; j < 8; ++j) acc[pi][j] = 0.f;

    for (int c = 0; c < 64; ++c) {
        const float4 d0 = *reinterpret_cast<const float4*>(D + c * 512 + lane * 8);
        const float4 d1 = *reinterpret_cast<const float4*>(D + c * 512 + lane * 8 + 4);
        #pragma unroll
        for (int pi = 0; pi < 4; ++pi) {
            const float pc = sp[pw + pi][c];
            acc[pi][0] += pc * d0.x; acc[pi][1] += pc * d0.y;
            acc[pi][2] += pc * d0.z; acc[pi][3] += pc * d0.w;
            acc[pi][4] += pc * d1.x; acc[pi][5] += pc * d1.y;
            acc[pi][6] += pc * d1.z; acc[pi][7] += pc * d1.w;
        }
    }

    #pragma unroll
    for (int pi = 0; pi < 4; ++pi) {
        float* Hp = H + (size_t)(p0 + pw + pi) * 512 + lane * 8;
        reinterpret_cast<float4*>(Hp)[0] = float4{acc[pi][0], acc[pi][1], acc[pi][2], acc[pi][3]};
        reinterpret_cast<float4*>(Hp)[1] = float4{acc[pi][4], acc[pi][5], acc[pi][6], acc[pi][7]};
    }
}

// ---------------- OMP iterations: one wave per patch ----------------
// f32 h/argmax/residual; f64 Gram solve. Lane owns atoms lane*8 + j.
__launch_bounds__(256)
__global__ void omp2_kernel(const float* __restrict__ ze,
                            const float* __restrict__ H,
                            const double* __restrict__ G,
                            const float* __restrict__ Gf,
                            const float* __restrict__ Dt,
                            float* __restrict__ out,
                            double* __restrict__ lpart) {
    __shared__ double lsum[4];
    const int wave = threadIdx.x >> 6;
    const int lane = threadIdx.x & 63;
    const int p    = blockIdx.x * 4 + wave;
    const int b    = p >> 12;
    const int hw   = p & 4095;

    const float pe = ze[(size_t)(b * 64 + lane) * 4096 + hw];

    // load h_bar (f32, 8 consecutive per lane)
    float hb[8], h[8];
    {
        const float4* Hp = reinterpret_cast<const float4*>(H + (size_t)p * 512 + lane * 8);
        float4 t0 = Hp[0], t1 = Hp[1];
        hb[0] = t0.x; hb[1] = t0.y; hb[2] = t0.z; hb[3] = t0.w;
        hb[4] = t1.x; hb[5] = t1.y; hb[6] = t1.z; hb[7] = t1.w;
    }
    #pragma unroll
    for (int j = 0; j < 8; ++j) h[j] = hb[j];

    unsigned mask = 0;
    int    a[5];
    double rhs[5];
    double x[5];

    #pragma unroll
    for (int k = 0; k < K_SP; ++k) {
        // ---- local argmax of |h| (f32, skip masked), lowest-n tie-break ----
        float bv = -1.0f; int bn = 0x7fffffff;
        #pragma unroll
        for (int j = 0; j < 8; ++j) {
            float av = fabsf(h[j]);
            bool ok = !((mask >> j) & 1u);
            int n = lane * 8 + j;
            if (ok && (av > bv || (av == bv && n < bn))) { bv = av; bn = n; }
        }
        // ---- wave argmax reduce ----
        #pragma unroll
        for (int off = 32; off > 0; off >>= 1) {
            float ov = __shfl_xor(bv, off);
            int   on = __shfl_xor(bn, off);
            if (ov > bv || (ov == bv && on < bn)) { bv = ov; bn = on; }
        }
        a[k] = bn;
        {
            const int src = bn >> 3, jj = bn & 7;
            float v = 0.f;
            #pragma unroll
            for (int j = 0; j < 8; ++j) if (j == jj) v = hb[j];
            rhs[k] = (double)__shfl(v, src);
            if (lane == src) mask |= (1u << jj);
        }

        // ---- solve (k+1)x(k+1) Gram system in f64, replicated on all lanes ----
        double T[5][5], y[5];
        #pragma unroll
        for (int i = 0; i <= k; ++i) {
            #pragma unroll
            for (int j2 = 0; j2 <= k; ++j2)
                T[i][j2] = G[(size_t)a[i] * 512 + a[j2]];
            y[i] = rhs[i];
        }
        #pragma unroll
        for (int col = 0; col <= k; ++col) {
            double inv = 1.0 / T[col][col];
            #pragma unroll
            for (int r = col + 1; r <= k; ++r) {
                double f = T[r][col] * inv;
                #pragma unroll
                for (int cc = col; cc <= k; ++cc)
                    T[r][cc] -= f * T[col][cc];
                y[r] -= f * y[col];
            }
        }
        #pragma unroll
        for (int r = k; r >= 0; --r) {
            double s = y[r];
            #pragma unroll
            for (int cc = r + 1; cc <= k; ++cc) s -= T[r][cc] * x[cc];
            x[r] = s / T[r][r];
        }

        // ---- residual (f32): h = hb - sum_i xf_i * Gf[a_i] (i ascending) ----
        if (k < K_SP - 1) {
            #pragma unroll
            for (int j = 0; j < 8; ++j) h[j] = hb[j];
            #pragma unroll
            for (int i = 0; i <= k; ++i) {
                const float4* gr = reinterpret_cast<const float4*>(Gf + (size_t)a[i] * 512 + lane * 8);
                float4 g0 = gr[0], g1 = gr[1];
                const float xi = (float)x[i];
                h[0] -= xi * g0.x; h[1] -= xi * g0.y;
                h[2] -= xi * g0.z; h[3] -= xi * g0.w;
                h[4] -= xi * g1.x; h[5] -= xi * g1.y;
                h[6] -= xi * g1.z; h[7] -= xi * g1.w;
            }
        }
    }

    // ---- scatter coeffs.T ----
    if (lane == 0) {
        #pragma unroll
        for (int i = 0; i < K_SP; ++i)
            out[(size_t)OUT_COEFF + (size_t)a[i] * 32768 + p] = (float)x[i];
    }

    // ---- recon, z_dl_st ----
    double rc = 0.0;
    #pragma unroll
    for (int i = 0; i < K_SP; ++i)
        rc += x[i] * (double)Dt[(size_t)a[i] * 64 + lane];
    const float zd = (float)rc;
    out[(size_t)(b * 64 + lane) * 4096 + hw] = pe + (zd - pe);

    // ---- loss: wave reduce -> block partial (no global atomic) ----
    const float df = zd - pe;
    double sq = (double)df * (double)df;
    #pragma unroll
    for (int off = 32; off > 0; off >>= 1)
        sq += __shfl_xor(sq, off);
    if (lane == 0) lsum[wave] = sq;
    __syncthreads();
    if (threadIdx.x == 0)
        lpart[blockIdx.x] = (lsum[0] + lsum[1]) + (lsum[2] + lsum[3]);
}

// ---------------- final loss reduction: 8192 f64 partials -> out[OUT_LOSS] ----
__global__ void loss_reduce(const double* __restrict__ lpart,
                            float* __restrict__ out) {
    __shared__ double ls[4];
    const int tid = threadIdx.x, wave = tid >> 6, lane = tid & 63;
    double s = 0.0;
    for (int i = tid; i < NBLOCKS_OMP; i += 256) s += lpart[i];
    #pragma unroll
    for (int off = 32; off > 0; off >>= 1)
        s += __shfl_xor(s, off);
    if (lane == 0) ls[wave] = s;
    __syncthreads();
    if (tid == 0)
        out[OUT_LOSS] = (float)(((ls[0] + ls[1]) + (ls[2] + ls[3])) * (1.25 / 2097152.0));
}

extern "C" void kernel_launch(void* const* d_in, const int* in_sizes, int n_in,
                              void* d_out, int out_size, void* d_ws, size_t ws_size,
                              hipStream_t stream) {
    const float* ze = (const float*)d_in[0];   // (8,64,64,64) f32
    const float* D  = (const float*)d_in[1];   // (64,512) f32, unit-norm cols
    float* out = (float*)d_out;

    const size_t H_BYTES  = (size_t)P_TOTAL * 512 * 4;   // 67108864 (f32)
    const size_t G_BYTES  = (size_t)512 * 512 * 8;       // 2097152
    const size_t GF_BYTES = (size_t)512 * 512 * 4;       // 1048576
    const size_t DT_BYTES = (size_t)512 * 64 * 4;        // 131072

    float*  H  = (float*)d_ws;
    double* G  = (double*)((char*)d_ws + H_BYTES);
    float*  Gf = (float*)((char*)d_ws + H_BYTES + G_BYTES);
    float*  Dt = (float*)((char*)d_ws + H_BYTES + G_BYTES + GF_BYTES);
    double* LP = (double*)((char*)d_ws + H_BYTES + G_BYTES + GF_BYTES + DT_BYTES);

    zero_tail<<<2048, 256, 0, stream>>>(out);
    prep_kernel<<<1024, 256, 0, stream>>>(D, G, Gf, Dt);
    hbar_kernel<<<P_TOTAL / 16, 256, 0, stream>>>(ze, D, H);
    omp2_kernel<<<NBLOCKS_OMP, 256, 0, stream>>>(ze, H, G, Gf, Dt, out, LP);
    loss_reduce<<<1, 256, 0, stream>>>(LP, out);
}